// Round 18
// baseline (297.724 us; speedup 1.0000x reference)
//
#include <hip/hip_runtime.h>
#include <stdint.h>
#include <math.h>

#define DEVI __device__ __forceinline__

typedef __attribute__((ext_vector_type(8))) short sv8;
typedef __attribute__((ext_vector_type(4))) short sv4;
typedef __attribute__((ext_vector_type(4))) float fv4;

typedef __attribute__((address_space(1))) void av1_t;
typedef __attribute__((address_space(3))) void av3_t;

constexpr int Bb = 2, Tt = 2048, Ee = 1024, Hh = 16, Dd = 64, FFd = 4096;
constexpr int NN = Bb * Tt;  // 4096 token rows
constexpr float EPSv = 1e-5f;

#define WAIT_VM(n) asm volatile("s_waitcnt vmcnt(" #n ")" ::: "memory")

DEVI float b2f(unsigned short s) {
  union { unsigned u; float f; } v; v.u = ((unsigned)s) << 16; return v.f;
}
DEVI unsigned short f2b(float f) {
  union { float f; unsigned u; } v; v.f = f;
  return (unsigned short)((v.u + 0x7FFFu + ((v.u >> 16) & 1u)) >> 16);
}
// pack two floats as bf16 pair (truncation), low = a, high = b
DEVI unsigned pkbf(float a, float b) {
  union { float f; unsigned u; } x, y; x.f = a; y.f = b;
  return (y.u & 0xFFFF0000u) | (x.u >> 16);
}

// global -> LDS direct (16B per lane). LDS dest must be wave-uniform base + lane*16.
DEVI void load_lds16(const void* g, void* s) {
  __builtin_amdgcn_global_load_lds((av1_t*)(unsigned long long)g,
                                   (av3_t*)(unsigned)(unsigned long long)s,
                                   16, 0, 0);
}

// ------------- merged weight convert: all 6 weights in ONE launch -------------
__global__ __launch_bounds__(256) void cvt_all_kernel(
    const float* __restrict__ Wq, const float* __restrict__ Wk,
    const float* __restrict__ Wv, const float* __restrict__ Wo,
    const float* __restrict__ W1, const float* __restrict__ W2,
    unsigned short* __restrict__ wqkv, unsigned short* __restrict__ wo16,
    unsigned short* __restrict__ w116, unsigned short* __restrict__ w216,
    float s2) {
  const int bid = blockIdx.x;
  if (bid < 4096) {
    const int wsel = bid >> 10;  // 0:Wq 1:Wk 2:Wv 3:Wo
    const int i = ((bid & 1023) * 256 + threadIdx.x) * 4;
    const float* src = (wsel == 0) ? Wq : (wsel == 1) ? Wk : (wsel == 2) ? Wv : Wo;
    unsigned short* dst = (wsel == 3) ? wo16 : (wqkv + (size_t)wsel * Ee * Ee);
    const float sc = (wsel == 0) ? s2 : 1.0f;
    const float4 v = *(const float4*)(src + i);
    sv4 o;
    o[0] = (short)f2b(v.x * sc); o[1] = (short)f2b(v.y * sc);
    o[2] = (short)f2b(v.z * sc); o[3] = (short)f2b(v.w * sc);
    *(sv4*)(dst + i) = o;
  } else if (bid < 12288) {
    const int i = ((bid - 4096) * 256 + threadIdx.x) * 4;  // flat over 2*FFd*Ee
    const int r = i >> 10, c = i & 1023;
    const int rp = (r < FFd) ? ((r >> 4) * 32 + (r & 15))
                             : (((r - FFd) >> 4) * 32 + 16 + (r & 15));
    const float4 v = *(const float4*)(W1 + i);
    sv4 o;
    o[0] = (short)f2b(v.x); o[1] = (short)f2b(v.y);
    o[2] = (short)f2b(v.z); o[3] = (short)f2b(v.w);
    *(sv4*)(w116 + (size_t)rp * Ee + c) = o;
  } else {
    const int i = ((bid - 12288) * 256 + threadIdx.x) * 4;  // flat over Ee*FFd
    const float4 v = *(const float4*)(W2 + i);
    sv4 o;
    o[0] = (short)f2b(v.x); o[1] = (short)f2b(v.y);
    o[2] = (short)f2b(v.z); o[3] = (short)f2b(v.w);
    *(sv4*)(w216 + i) = o;
  }
}

// ------- V transpose with k' permutation: qkv V-slice [t][h*64+d] -> vT[b][h][d][k'] -
// k' = 32*(ks>>1) + 8*g + 4*(ks&1) + jj for token k = 16ks+4g+jj within each 64-tile.
__global__ __launch_bounds__(256) void vt_kernel(const unsigned short* __restrict__ qkv,
                                                 unsigned short* __restrict__ vT) {
  const int bh = blockIdx.y;               // b*16+h
  const int b = bh >> 4, h = bh & 15;
  const int tt = blockIdx.x * 64;          // token tile
  const int tid = threadIdx.x;
  __shared__ unsigned short tile[64][65];  // +1 pad
  const int tr = tid >> 2, tc4 = (tid & 3) * 16;
  const unsigned short* src = qkv + (size_t)(b * Tt + tt + tr) * (3 * Ee) + 2 * Ee + h * 64 + tc4;
  const sv8 a0 = *(const sv8*)src;
  const sv8 a1 = *(const sv8*)(src + 8);
#pragma unroll
  for (int j = 0; j < 8; ++j) { tile[tr][tc4 + j] = a0[j]; tile[tr][tc4 + 8 + j] = a1[j]; }
  __syncthreads();
  const int ks = tid & 3;
  const int koff = 32 * (ks >> 1) + 4 * (ks & 1);
  unsigned short* dst = vT + ((size_t)bh * 64 + tr) * Tt + tt + koff;
#pragma unroll
  for (int g = 0; g < 4; ++g) {
    sv4 v;
#pragma unroll
    for (int jj = 0; jj < 4; ++jj) v[jj] = (short)tile[tc4 + 4 * g + jj][tr];
    *(sv4*)(dst + 8 * g) = v;
  }
}

// ---------------- LayerNorm (fp32 in, bf16 out), one block per row ----------------
__global__ __launch_bounds__(256) void ln_kernel(const float* __restrict__ x,
                                                 const float* __restrict__ g,
                                                 const float* __restrict__ b,
                                                 unsigned short* __restrict__ out) {
  const int row = blockIdx.x, tid = threadIdx.x;
  const float4 v = *(const float4*)(x + (size_t)row * Ee + tid * 4);
  float s = v.x + v.y + v.z + v.w;
  float ss = v.x * v.x + v.y * v.y + v.z * v.z + v.w * v.w;
#pragma unroll
  for (int off = 32; off; off >>= 1) { s += __shfl_down(s, off); ss += __shfl_down(ss, off); }
  __shared__ float red[16];
  const int w = tid >> 6, l = tid & 63;
  if (l == 0) { red[w] = s; red[8 + w] = ss; }
  __syncthreads();
  s = red[0] + red[1] + red[2] + red[3];
  ss = red[8] + red[9] + red[10] + red[11];
  const float mean = s * (1.f / Ee);
  const float rstd = rsqrtf(ss * (1.f / Ee) - mean * mean + EPSv);
  const float4 gv = *(const float4*)(g + tid * 4);
  const float4 bv = *(const float4*)(b + tid * 4);
  sv4 o;
  o[0] = (short)f2b((v.x - mean) * rstd * gv.x + bv.x);
  o[1] = (short)f2b((v.y - mean) * rstd * gv.y + bv.y);
  o[2] = (short)f2b((v.z - mean) * rstd * gv.z + bv.z);
  o[3] = (short)f2b((v.w - mean) * rstd * gv.w + bv.w);
  *(sv4*)(out + (size_t)row * Ee + tid * 4) = o;
}

// ---------------- bf16 GEMM (128xBN, 4 waves) — QKV / Wo / W2 ----------------
template <int OUTF32, int HASBIAS, int BN, int GEGLU>
__global__ __launch_bounds__(256) void gemm_bt(const unsigned short* __restrict__ A,
                                               const unsigned short* __restrict__ Bw,
                                               void* __restrict__ Cout,
                                               const float* __restrict__ bias,
                                               const float* __restrict__ res,
                                               int M, int K) {
  constexpr int NI = BN / 32;  // per-wave n-frags (wave covers BN/2 cols)
  __shared__ unsigned short lA[3][128 * 32];
  __shared__ unsigned short lB[3][BN * 32];
  const int tid = threadIdx.x;
  const int l = tid & 63, w = tid >> 6;
  const int wr = w >> 1, wc = w & 1;
  const int rowbase = blockIdx.y * 128, colbase = blockIdx.x * BN;

  const fv4 zero4 = {0.f, 0.f, 0.f, 0.f};
  fv4 acc[4][NI];
#pragma unroll
  for (int i = 0; i < 4; ++i)
#pragma unroll
    for (int j = 0; j < NI; ++j) acc[i][j] = zero4;

  const int c0 = tid, c1 = tid + 256;
  const int sw0 = ((c0 & 3) ^ ((c0 >> 3) & 3)) * 8;
  const int sw1 = ((c1 & 3) ^ ((c1 >> 3) & 3)) * 8;
  const unsigned short* Ag0 = A + (size_t)(rowbase + (c0 >> 2)) * K + sw0;
  const unsigned short* Ag1 = A + (size_t)(rowbase + (c1 >> 2)) * K + sw1;
  const unsigned short* Bg0 = Bw + (size_t)(colbase + (c0 >> 2)) * K + sw0;
  const unsigned short* Bg1 = Bw + (size_t)(colbase + ((BN == 128 ? c1 : c0) >> 2)) * K +
                              (BN == 128 ? sw1 : sw0);

  const int nk = K >> 5;

  auto stage = [&](int buf) {
    load_lds16(Ag0, lA[buf] + c0 * 8);
    load_lds16(Ag1, lA[buf] + c1 * 8);
    load_lds16(Bg0, lB[buf] + c0 * 8);
    if (BN == 128) load_lds16(Bg1, lB[buf] + c1 * 8);
    Ag0 += 32; Ag1 += 32; Bg0 += 32; Bg1 += 32;
  };

  stage(0);
  stage(1);
  if constexpr (BN == 128) WAIT_VM(4); else WAIT_VM(3);
  __builtin_amdgcn_s_barrier();

  int cur = 0;
  for (int t = 0; t < nk; ++t) {
    const int pf = (cur + 2 >= 3) ? cur - 1 : cur + 2;  // (cur+2)%3
    if (t + 2 < nk) stage(pf);
    sv8 af[4], bfr[NI];
#pragma unroll
    for (int i = 0; i < 4; ++i) {
      const int ra = wr * 64 + i * 16 + (l & 15);
      af[i] = *(const sv8*)(lA[cur] + ra * 32 + (((l >> 4) ^ ((ra >> 1) & 3)) * 8));
    }
#pragma unroll
    for (int i = 0; i < NI; ++i) {
      const int rb = wc * (BN / 2) + i * 16 + (l & 15);
      bfr[i] = *(const sv8*)(lB[cur] + rb * 32 + (((l >> 4) ^ ((rb >> 1) & 3)) * 8));
    }
    __builtin_amdgcn_s_setprio(1);
#pragma unroll
    for (int mi = 0; mi < 4; ++mi)
#pragma unroll
      for (int ni = 0; ni < NI; ++ni)
        acc[mi][ni] = __builtin_amdgcn_mfma_f32_16x16x32_bf16(af[mi], bfr[ni], acc[mi][ni], 0, 0, 0);
    __builtin_amdgcn_s_setprio(0);
    if (t + 2 < nk) {
      if constexpr (BN == 128) WAIT_VM(4); else WAIT_VM(3);
      __builtin_amdgcn_s_barrier();
    } else if (t + 1 < nk) {
      WAIT_VM(0);
      __builtin_amdgcn_s_barrier();
    }
    cur = (cur + 1 >= 3) ? 0 : cur + 1;
  }

  const int r0 = rowbase + wr * 64 + ((l >> 4) * 4);
  const int ccol = colbase + wc * (BN / 2) + (l & 15);
#pragma unroll
  for (int mi = 0; mi < 4; ++mi) {
#pragma unroll
    for (int j = 0; j < 4; ++j) {
      const size_t r = (size_t)(r0 + mi * 16 + j);
      if (GEGLU) {
#pragma unroll
        for (int p = 0; p < NI / 2; ++p) {
          const int ca = ccol + p * 32;
          const int ocol = ((ca >> 5) << 4) | (ca & 15);
          const float av = acc[mi][2 * p][j] + bias[ocol];
          const float gv = acc[mi][2 * p + 1][j] + bias[ocol + (M >> 1)];
          const float y = 0.7978845608028654f * (gv + 0.044715f * gv * gv * gv);
          const float e = exp2f(2.8853900817779268f * y);
          const float gel = gv * (1.f - 1.f / (e + 1.f));
          ((unsigned short*)Cout)[r * (size_t)(M >> 1) + ocol] = f2b(av * gel);
        }
      } else {
#pragma unroll
        for (int ni = 0; ni < NI; ++ni) {
          const int c = ccol + ni * 16;
          float vv = acc[mi][ni][j];
          if (HASBIAS) vv += bias[c];
          if (OUTF32) {
            ((float*)Cout)[r * M + c] = res[r * M + c] + vv;
          } else {
            ((unsigned short*)Cout)[r * M + c] = f2b(vv);
          }
        }
      }
    }
  }
}

// ------- 256x128 8-wave GEMM, 2-buffer depth-1 prefetch, 3 blocks/CU — W1 -------
template <int GEGLU>
__global__ __launch_bounds__(512, 4) void gemm256(const unsigned short* __restrict__ A,
                                                  const unsigned short* __restrict__ Bw,
                                                  void* __restrict__ Cout,
                                                  const float* __restrict__ bias,
                                                  int M, int K) {
  __shared__ unsigned short Ah[2][256 * 32];
  __shared__ unsigned short Bh[2][128 * 32];
  const int tid = threadIdx.x;
  const int l = tid & 63, w = tid >> 6;
  const int wrow = w >> 2, wcol = w & 3;   // 2 x 4 wave grid
  const int nbase = blockIdx.y * 256, mbase = blockIdx.x * 128;

  const fv4 zero4 = {0.f, 0.f, 0.f, 0.f};
  fv4 acc[8][2];
#pragma unroll
  for (int i = 0; i < 8; ++i) { acc[i][0] = zero4; acc[i][1] = zero4; }

  const int sA0 = tid, sA1 = tid + 512;
  const int rA0 = sA0 >> 2, xA0 = ((sA0 & 3) ^ ((rA0 >> 1) & 3)) * 8;
  const int rA1 = sA1 >> 2, xA1 = ((sA1 & 3) ^ ((rA1 >> 1) & 3)) * 8;
  const int rB = tid >> 2, xB = ((tid & 3) ^ ((rB >> 1) & 3)) * 8;
  const unsigned short* As0 = A + (size_t)(nbase + rA0) * K + xA0;
  const unsigned short* As1 = A + (size_t)(nbase + rA1) * K + xA1;
  const unsigned short* Bs = Bw + (size_t)(mbase + rB) * K + xB;

  const int nk = K >> 5;

  auto stage = [&](int buf, int kof) {
    load_lds16(As0 + kof, &Ah[buf][sA0 * 8]);
    load_lds16(As1 + kof, &Ah[buf][sA1 * 8]);
    load_lds16(Bs + kof, &Bh[buf][tid * 8]);
  };

  const int cl = (((l >> 4) ^ ((l >> 1) & 3))) * 8;
  const int arl = (wrow * 128 + (l & 15)) * 32 + cl;
  const int brl = (wcol * 32 + (l & 15)) * 32 + cl;

  stage(0, 0);
  __syncthreads();

  int cur = 0;
  for (int t = 0; t < nk; ++t) {
    const int nx = cur ^ 1;
    if (t + 1 < nk) stage(nx, (t + 1) * 32);
    sv8 af[8], b0, b1;
#pragma unroll
    for (int mi = 0; mi < 8; ++mi) af[mi] = *(const sv8*)(&Ah[cur][arl + mi * 512]);
    b0 = *(const sv8*)(&Bh[cur][brl]);
    b1 = *(const sv8*)(&Bh[cur][brl + 512]);
    __builtin_amdgcn_s_setprio(1);
#pragma unroll
    for (int mi = 0; mi < 8; ++mi) {
      acc[mi][0] = __builtin_amdgcn_mfma_f32_16x16x32_bf16(af[mi], b0, acc[mi][0], 0, 0, 0);
      acc[mi][1] = __builtin_amdgcn_mfma_f32_16x16x32_bf16(af[mi], b1, acc[mi][1], 0, 0, 0);
    }
    __builtin_amdgcn_s_setprio(0);
    __syncthreads();  // drains prefetch; all waves done reading buf[cur]
    cur = nx;
  }

  const int rbase = nbase + wrow * 128 + ((l >> 4) * 4);
  const int cbase = mbase + wcol * 32 + (l & 15);
#pragma unroll
  for (int mi = 0; mi < 8; ++mi) {
#pragma unroll
    for (int j = 0; j < 4; ++j) {
      const size_t r = (size_t)(rbase + mi * 16 + j);
      if (GEGLU) {
        const int ca = cbase;                            // even fragment (a); bit4 == 0
        const int ocol = ((ca >> 5) << 4) | (ca & 15);   // original column
        const float av = acc[mi][0][j] + bias[ocol];
        const float gv = acc[mi][1][j] + bias[ocol + (M >> 1)];
        const float y = 0.7978845608028654f * (gv + 0.044715f * gv * gv * gv);
        const float e = exp2f(2.8853900817779268f * y);  // exp(2y)
        const float gel = gv * (1.f - 1.f / (e + 1.f));  // == 0.5*g*(1+tanh(y))
        ((unsigned short*)Cout)[r * (size_t)(M >> 1) + ocol] = f2b(av * gel);
      } else {
#pragma unroll
        for (int ni = 0; ni < 2; ++ni) {
          const int c = cbase + ni * 16;
          ((unsigned short*)Cout)[r * (size_t)M + c] = f2b(acc[mi][ni][j]);
        }
      }
    }
  }
}

// ------ flash attention, swapped QK^T, in-register P, KVBLK=128 ------
// 16 iterations (was 32): halves the prefetch-drain barriers and staging-addr VALU;
// each prefetch has the full 32-MFMA compute window to land. K tile [128][64] staged
// as before (8-chunk rows, ^(row&7)); V tile [64 d][128 k'] with 16-chunk rows and
// chunk' = chunk ^ (row&15) (same 2-lanes/bank arithmetic). P packs to 4 sv8 frags.
__global__ __launch_bounds__(256) void attn_kernel(const unsigned short* __restrict__ Q,
                                                   const unsigned short* __restrict__ Kb,
                                                   const unsigned short* __restrict__ vT,
                                                   unsigned short* __restrict__ O,
                                                   int ld) {
  const int bidl = ((blockIdx.x & 7) << 7) + (blockIdx.x >> 3);  // 1024 = 8 XCD x 128
  const int bh = bidl >> 5;
  const int b = bh / Hh, h = bh % Hh;
  const int q0 = (bidl & 31) * 64;
  const int tid = threadIdx.x, l = tid & 63, w = tid >> 6;
  const size_t base = (size_t)b * Tt * ld + (size_t)h * Dd;
  const size_t baseO = (size_t)b * Tt * Ee + (size_t)h * Dd;
  const unsigned short* vTb = vT + (size_t)bh * 64 * Tt;  // [64 d][2048 k']

  __shared__ unsigned short Kt[2][128 * 64];  // [token][d]
  __shared__ unsigned short Vt[2][64 * 128];  // [d][k']

  sv8 qf0, qf1;
  {
    const unsigned short* qp = Q + base + (size_t)(q0 + w * 16 + (l & 15)) * ld + (l >> 4) * 8;
    qf0 = *(const sv8*)qp;
    qf1 = *(const sv8*)(qp + 32);
  }

  const fv4 zero4 = {0.f, 0.f, 0.f, 0.f};
  fv4 acc_o[4];
#pragma unroll
  for (int i = 0; i < 4; ++i) acc_o[i] = zero4;
  float Mx = -INFINITY, Lp = 0.f;

  // staging indices: 4 chunks per thread per operand (1024 chunks each)
  int rK[4], xK[4], rV[4], xV[4];
#pragma unroll
  for (int i = 0; i < 4; ++i) {
    const int c = tid + 256 * i;
    rK[i] = c >> 3; xK[i] = ((c & 7) ^ (rK[i] & 7)) * 8;
    rV[i] = c >> 4; xV[i] = ((c & 15) ^ (rV[i] & 15)) * 8;
  }

  auto stageKV = [&](int buf, int kt) {
#pragma unroll
    for (int i = 0; i < 4; ++i)
      load_lds16(Kb + base + (size_t)(kt * 128 + rK[i]) * ld + xK[i], Kt[buf] + (tid + 256 * i) * 8);
#pragma unroll
    for (int i = 0; i < 4; ++i)
      load_lds16(vTb + (size_t)rV[i] * Tt + kt * 128 + xV[i], Vt[buf] + (tid + 256 * i) * 8);
  };

  stageKV(0, 0);
  __syncthreads();

  int cur = 0;
  for (int kt = 0; kt < Tt / 128; ++kt) {
    const int nx = cur ^ 1;
    if (kt + 1 < Tt / 128) stageKV(nx, kt + 1);

    // --- S^T = K Q^T over 128 k-rows: st[ks] for ks 0..7 ---
    fv4 st[8];
    __builtin_amdgcn_s_setprio(1);
#pragma unroll
    for (int ks = 0; ks < 8; ++ks) {
      const int row = ks * 16 + (l & 15);
      const sv8 kf0 = *(const sv8*)(Kt[cur] + row * 64 + (((l >> 4) ^ (row & 7)) * 8));
      const sv8 kf1 = *(const sv8*)(Kt[cur] + row * 64 + (((4 + (l >> 4)) ^ (row & 7)) * 8));
      fv4 t = zero4;
      t = __builtin_amdgcn_mfma_f32_16x16x32_bf16(kf0, qf0, t, 0, 0, 0);
      t = __builtin_amdgcn_mfma_f32_16x16x32_bf16(kf1, qf1, t, 0, 0, 0);
      st[ks] = t;
    }
    __builtin_amdgcn_s_setprio(0);

    // --- per-q max (lane-local tree over 32 + 2 cross-quarter shuffles) ---
    float tm = -INFINITY;
#pragma unroll
    for (int ks = 0; ks < 8; ++ks)
      tm = fmaxf(tm, fmaxf(fmaxf(st[ks][0], st[ks][1]), fmaxf(st[ks][2], st[ks][3])));
    tm = fmaxf(tm, __shfl_xor(tm, 16));
    tm = fmaxf(tm, __shfl_xor(tm, 32));
    if (__any(tm > Mx + 11.5f)) {
      const float mnew = fmaxf(Mx, tm);
      const float alpha = exp2f(Mx - mnew);  // tile 0: exp2(-inf) = 0
      Mx = mnew;
      Lp *= alpha;
#pragma unroll
      for (int j = 0; j < 4; ++j) {
        const float aj = __shfl(alpha, (l & 48) | ((l >> 4) * 4 + j));
#pragma unroll
        for (int dsb = 0; dsb < 4; ++dsb) acc_o[dsb][j] *= aj;
      }
    }
    // --- p = exp2(s - Mx); lane-local denominator; pack to 4 A-fragments ---
    union PA { sv8 v8; unsigned u[4]; } pa[4];
#pragma unroll
    for (int ks = 0; ks < 8; ++ks) {
#pragma unroll
      for (int jp = 0; jp < 2; ++jp) {
        const float p0 = exp2f(st[ks][2 * jp] - Mx);
        const float p1 = exp2f(st[ks][2 * jp + 1] - Mx);
        Lp += p0 + p1;
        pa[ks >> 1].u[(ks & 1) * 2 + jp] = pkbf(p0, p1);
      }
    }

    // --- O += P V over 128 k' (V rows [64 d][128 k'], chunk' = gc ^ (row&15)) ---
    __builtin_amdgcn_s_setprio(1);
#pragma unroll
    for (int kcn = 0; kcn < 4; ++kcn) {
      const sv8 pf = pa[kcn].v8;
#pragma unroll
      for (int dsb = 0; dsb < 4; ++dsb) {
        const int row = dsb * 16 + (l & 15);
        const int gc = kcn * 4 + (l >> 4);
        const sv8 vf = *(const sv8*)(Vt[cur] + row * 128 + ((gc ^ (row & 15)) * 8));
        acc_o[dsb] = __builtin_amdgcn_mfma_f32_16x16x32_bf16(pf, vf, acc_o[dsb], 0, 0, 0);
      }
    }
    __builtin_amdgcn_s_setprio(0);

    __syncthreads();  // drains prefetch; all waves done reading [cur]
    cur = nx;
  }

  // ---- denominator: cross-quarter reduce, broadcast to output lanes ----
  float Lt = Lp;
  Lt += __shfl_xor(Lt, 16);
  Lt += __shfl_xor(Lt, 32);
#pragma unroll
  for (int j = 0; j < 4; ++j) {
    const float Lj = __shfl(Lt, (l & 48) | ((l >> 4) * 4 + j));
    const float inv = 1.f / Lj;
    unsigned short* op = O + baseO + (size_t)(q0 + w * 16 + (l >> 4) * 4 + j) * Ee;
#pragma unroll
    for (int dsb = 0; dsb < 4; ++dsb)
      op[dsb * 16 + (l & 15)] = f2b(acc_o[dsb][j] * inv);
  }
}

extern "C" void kernel_launch(void* const* d_in, const int* in_sizes, int n_in,
                              void* d_out, int out_size, void* d_ws, size_t ws_size,
                              hipStream_t stream) {
  (void)in_sizes; (void)n_in; (void)out_size; (void)ws_size;
  const float* src  = (const float*)d_in[0];
  const float* Wq   = (const float*)d_in[1];
  const float* Wk   = (const float*)d_in[2];
  const float* Wv   = (const float*)d_in[3];
  const float* Wo   = (const float*)d_in[4];
  const float* W1   = (const float*)d_in[5];
  const float* b1   = (const float*)d_in[6];
  const float* W2   = (const float*)d_in[7];
  const float* b2   = (const float*)d_in[8];
  const float* ln1w = (const float*)d_in[9];
  const float* ln1b = (const float*)d_in[10];
  const float* ln2w = (const float*)d_in[11];
  const float* ln2b = (const float*)d_in[12];
  float* out = (float*)d_out;

  char* ws = (char*)d_ws;
  size_t off = 0;
  auto alloc = [&](size_t bytes) { char* p = ws + off; off += bytes; return p; };
  unsigned short* wqkv = (unsigned short*)alloc((size_t)3 * Ee * Ee * 2);  // Wq|Wk|Wv rows
  unsigned short* wo16 = (unsigned short*)alloc((size_t)Ee * Ee * 2);
  unsigned short* w116 = (unsigned short*)alloc((size_t)2 * FFd * Ee * 2); // interleaved
  unsigned short* w216 = (unsigned short*)alloc((size_t)Ee * FFd * 2);
  unsigned short* h16  = (unsigned short*)alloc((size_t)NN * Ee * 2);
  unsigned short* qkv  = (unsigned short*)alloc((size_t)NN * 3 * Ee * 2);  // [row][3E]
  unsigned short* a16  = (unsigned short*)alloc((size_t)NN * Ee * 2);
  float* xbuf          = (float*)alloc((size_t)NN * Ee * 4);
  unsigned short* vT   = (unsigned short*)alloc((size_t)NN * Ee * 2);      // [b][h][64][T]
  unsigned short* f16  = qkv;  // reuse qkv+a16 region (32 MB) after attention done

  const float s2 = 0.125f * 1.4426950408889634f;  // 1/sqrt(D) * log2(e), folded into Wq

  dim3 blk(256);
  // all 6 weight converts in one launch
  cvt_all_kernel<<<dim3(16384), blk, 0, stream>>>(Wq, Wk, Wv, Wo, W1, W2,
                                                  wqkv, wo16, w116, w216, s2);

  ln_kernel<<<dim3(NN), blk, 0, stream>>>(src, ln1w, ln1b, h16);

  // fused QKV projection: [4096,1024] x [3072,1024]^T -> [4096,3072]
  gemm_bt<0, 0, 128, 0><<<dim3(3 * Ee / 128, NN / 128), blk, 0, stream>>>(h16, wqkv, qkv, nullptr, nullptr, 3 * Ee, Ee);

  // V transpose + k' permutation: [t][h*64+d] -> vT[b][h][d][k']
  vt_kernel<<<dim3(Tt / 64, Bb * Hh), blk, 0, stream>>>(qkv, vT);

  attn_kernel<<<dim3(1024), blk, 0, stream>>>(qkv, qkv + Ee, vT, a16, 3 * Ee);

  // Wo projection + residual (BN=64: 512 blocks, 2/CU)
  gemm_bt<1, 0, 64, 0><<<dim3(Ee / 64, NN / 128), blk, 0, stream>>>(a16, wo16, xbuf, nullptr, src, Ee, Ee);

  ln_kernel<<<dim3(NN), blk, 0, stream>>>(xbuf, ln2w, ln2b, h16);

  // W1 (block-16 interleaved) + lane-local GEGLU, 256x128 2-buffer kernel, 3 blocks/CU
  gemm256<1><<<dim3(2 * FFd / 128, NN / 256), dim3(512), 0, stream>>>(h16, w116, f16, b1, 2 * FFd, Ee);

  // W2 projection + bias + residual (BN=64: 512 blocks, 2/CU)
  gemm_bt<1, 1, 64, 0><<<dim3(Ee / 64, NN / 128), blk, 0, stream>>>(f16, w216, out, b2, xbuf, Ee, FFd);
}

// Round 19
// 291.519 us; speedup vs baseline: 1.0213x; 1.0213x over previous
//
#include <hip/hip_runtime.h>
#include <stdint.h>
#include <math.h>

#define DEVI __device__ __forceinline__

typedef __attribute__((ext_vector_type(8))) short sv8;
typedef __attribute__((ext_vector_type(4))) short sv4;
typedef __attribute__((ext_vector_type(4))) float fv4;

typedef __attribute__((address_space(1))) void av1_t;
typedef __attribute__((address_space(3))) void av3_t;

constexpr int Bb = 2, Tt = 2048, Ee = 1024, Hh = 16, Dd = 64, FFd = 4096;
constexpr int NN = Bb * Tt;  // 4096 token rows
constexpr float EPSv = 1e-5f;

#define WAIT_VM(n) asm volatile("s_waitcnt vmcnt(" #n ")" ::: "memory")

DEVI float b2f(unsigned short s) {
  union { unsigned u; float f; } v; v.u = ((unsigned)s) << 16; return v.f;
}
DEVI unsigned short f2b(float f) {
  union { float f; unsigned u; } v; v.f = f;
  return (unsigned short)((v.u + 0x7FFFu + ((v.u >> 16) & 1u)) >> 16);
}
// pack two floats as bf16 pair (truncation): one v_perm_b32 (low = a.hi16, high = b.hi16)
DEVI unsigned pkbf(float a, float b) {
  union { float f; unsigned u; } x, y; x.f = a; y.f = b;
  return __builtin_amdgcn_perm(y.u, x.u, 0x07060302u);
}

// global -> LDS direct (16B per lane). LDS dest must be wave-uniform base + lane*16.
DEVI void load_lds16(const void* g, void* s) {
  __builtin_amdgcn_global_load_lds((av1_t*)(unsigned long long)g,
                                   (av3_t*)(unsigned)(unsigned long long)s,
                                   16, 0, 0);
}

// ------------- merged weight convert: all 6 weights in ONE launch -------------
__global__ __launch_bounds__(256) void cvt_all_kernel(
    const float* __restrict__ Wq, const float* __restrict__ Wk,
    const float* __restrict__ Wv, const float* __restrict__ Wo,
    const float* __restrict__ W1, const float* __restrict__ W2,
    unsigned short* __restrict__ wqkv, unsigned short* __restrict__ wo16,
    unsigned short* __restrict__ w116, unsigned short* __restrict__ w216,
    float s2) {
  const int bid = blockIdx.x;
  if (bid < 4096) {
    const int wsel = bid >> 10;  // 0:Wq 1:Wk 2:Wv 3:Wo
    const int i = ((bid & 1023) * 256 + threadIdx.x) * 4;
    const float* src = (wsel == 0) ? Wq : (wsel == 1) ? Wk : (wsel == 2) ? Wv : Wo;
    unsigned short* dst = (wsel == 3) ? wo16 : (wqkv + (size_t)wsel * Ee * Ee);
    const float sc = (wsel == 0) ? s2 : 1.0f;
    const float4 v = *(const float4*)(src + i);
    sv4 o;
    o[0] = (short)f2b(v.x * sc); o[1] = (short)f2b(v.y * sc);
    o[2] = (short)f2b(v.z * sc); o[3] = (short)f2b(v.w * sc);
    *(sv4*)(dst + i) = o;
  } else if (bid < 12288) {
    const int i = ((bid - 4096) * 256 + threadIdx.x) * 4;  // flat over 2*FFd*Ee
    const int r = i >> 10, c = i & 1023;
    const int rp = (r < FFd) ? ((r >> 4) * 32 + (r & 15))
                             : (((r - FFd) >> 4) * 32 + 16 + (r & 15));
    const float4 v = *(const float4*)(W1 + i);
    sv4 o;
    o[0] = (short)f2b(v.x); o[1] = (short)f2b(v.y);
    o[2] = (short)f2b(v.z); o[3] = (short)f2b(v.w);
    *(sv4*)(w116 + (size_t)rp * Ee + c) = o;
  } else {
    const int i = ((bid - 12288) * 256 + threadIdx.x) * 4;  // flat over Ee*FFd
    const float4 v = *(const float4*)(W2 + i);
    sv4 o;
    o[0] = (short)f2b(v.x); o[1] = (short)f2b(v.y);
    o[2] = (short)f2b(v.z); o[3] = (short)f2b(v.w);
    *(sv4*)(w216 + i) = o;
  }
}

// ------- V transpose with k' permutation: qkv V-slice [t][h*64+d] -> vT[b][h][d][k'] -
// k' = 32*(ks>>1) + 8*g + 4*(ks&1) + jj for token k = 16ks+4g+jj within each 64-tile.
__global__ __launch_bounds__(256) void vt_kernel(const unsigned short* __restrict__ qkv,
                                                 unsigned short* __restrict__ vT) {
  const int bh = blockIdx.y;               // b*16+h
  const int b = bh >> 4, h = bh & 15;
  const int tt = blockIdx.x * 64;          // token tile
  const int tid = threadIdx.x;
  __shared__ unsigned short tile[64][65];  // +1 pad
  const int tr = tid >> 2, tc4 = (tid & 3) * 16;
  const unsigned short* src = qkv + (size_t)(b * Tt + tt + tr) * (3 * Ee) + 2 * Ee + h * 64 + tc4;
  const sv8 a0 = *(const sv8*)src;
  const sv8 a1 = *(const sv8*)(src + 8);
#pragma unroll
  for (int j = 0; j < 8; ++j) { tile[tr][tc4 + j] = a0[j]; tile[tr][tc4 + 8 + j] = a1[j]; }
  __syncthreads();
  const int ks = tid & 3;
  const int koff = 32 * (ks >> 1) + 4 * (ks & 1);
  unsigned short* dst = vT + ((size_t)bh * 64 + tr) * Tt + tt + koff;
#pragma unroll
  for (int g = 0; g < 4; ++g) {
    sv4 v;
#pragma unroll
    for (int jj = 0; jj < 4; ++jj) v[jj] = (short)tile[tc4 + 4 * g + jj][tr];
    *(sv4*)(dst + 8 * g) = v;
  }
}

// ---------------- LayerNorm (fp32 in, bf16 out), one block per row ----------------
__global__ __launch_bounds__(256) void ln_kernel(const float* __restrict__ x,
                                                 const float* __restrict__ g,
                                                 const float* __restrict__ b,
                                                 unsigned short* __restrict__ out) {
  const int row = blockIdx.x, tid = threadIdx.x;
  const float4 v = *(const float4*)(x + (size_t)row * Ee + tid * 4);
  float s = v.x + v.y + v.z + v.w;
  float ss = v.x * v.x + v.y * v.y + v.z * v.z + v.w * v.w;
#pragma unroll
  for (int off = 32; off; off >>= 1) { s += __shfl_down(s, off); ss += __shfl_down(ss, off); }
  __shared__ float red[16];
  const int w = tid >> 6, l = tid & 63;
  if (l == 0) { red[w] = s; red[8 + w] = ss; }
  __syncthreads();
  s = red[0] + red[1] + red[2] + red[3];
  ss = red[8] + red[9] + red[10] + red[11];
  const float mean = s * (1.f / Ee);
  const float rstd = rsqrtf(ss * (1.f / Ee) - mean * mean + EPSv);
  const float4 gv = *(const float4*)(g + tid * 4);
  const float4 bv = *(const float4*)(b + tid * 4);
  sv4 o;
  o[0] = (short)f2b((v.x - mean) * rstd * gv.x + bv.x);
  o[1] = (short)f2b((v.y - mean) * rstd * gv.y + bv.y);
  o[2] = (short)f2b((v.z - mean) * rstd * gv.z + bv.z);
  o[3] = (short)f2b((v.w - mean) * rstd * gv.w + bv.w);
  *(sv4*)(out + (size_t)row * Ee + tid * 4) = o;
}

// ---------------- bf16 GEMM (128xBN, 4 waves) — QKV / Wo / W2 ----------------
template <int OUTF32, int HASBIAS, int BN, int GEGLU>
__global__ __launch_bounds__(256) void gemm_bt(const unsigned short* __restrict__ A,
                                               const unsigned short* __restrict__ Bw,
                                               void* __restrict__ Cout,
                                               const float* __restrict__ bias,
                                               const float* __restrict__ res,
                                               int M, int K) {
  constexpr int NI = BN / 32;  // per-wave n-frags (wave covers BN/2 cols)
  __shared__ unsigned short lA[3][128 * 32];
  __shared__ unsigned short lB[3][BN * 32];
  const int tid = threadIdx.x;
  const int l = tid & 63, w = tid >> 6;
  const int wr = w >> 1, wc = w & 1;
  const int rowbase = blockIdx.y * 128, colbase = blockIdx.x * BN;

  const fv4 zero4 = {0.f, 0.f, 0.f, 0.f};
  fv4 acc[4][NI];
#pragma unroll
  for (int i = 0; i < 4; ++i)
#pragma unroll
    for (int j = 0; j < NI; ++j) acc[i][j] = zero4;

  const int c0 = tid, c1 = tid + 256;
  const int sw0 = ((c0 & 3) ^ ((c0 >> 3) & 3)) * 8;
  const int sw1 = ((c1 & 3) ^ ((c1 >> 3) & 3)) * 8;
  const unsigned short* Ag0 = A + (size_t)(rowbase + (c0 >> 2)) * K + sw0;
  const unsigned short* Ag1 = A + (size_t)(rowbase + (c1 >> 2)) * K + sw1;
  const unsigned short* Bg0 = Bw + (size_t)(colbase + (c0 >> 2)) * K + sw0;
  const unsigned short* Bg1 = Bw + (size_t)(colbase + ((BN == 128 ? c1 : c0) >> 2)) * K +
                              (BN == 128 ? sw1 : sw0);

  const int nk = K >> 5;

  auto stage = [&](int buf) {
    load_lds16(Ag0, lA[buf] + c0 * 8);
    load_lds16(Ag1, lA[buf] + c1 * 8);
    load_lds16(Bg0, lB[buf] + c0 * 8);
    if (BN == 128) load_lds16(Bg1, lB[buf] + c1 * 8);
    Ag0 += 32; Ag1 += 32; Bg0 += 32; Bg1 += 32;
  };

  stage(0);
  stage(1);
  if constexpr (BN == 128) WAIT_VM(4); else WAIT_VM(3);
  __builtin_amdgcn_s_barrier();

  int cur = 0;
  for (int t = 0; t < nk; ++t) {
    const int pf = (cur + 2 >= 3) ? cur - 1 : cur + 2;  // (cur+2)%3
    if (t + 2 < nk) stage(pf);
    sv8 af[4], bfr[NI];
#pragma unroll
    for (int i = 0; i < 4; ++i) {
      const int ra = wr * 64 + i * 16 + (l & 15);
      af[i] = *(const sv8*)(lA[cur] + ra * 32 + (((l >> 4) ^ ((ra >> 1) & 3)) * 8));
    }
#pragma unroll
    for (int i = 0; i < NI; ++i) {
      const int rb = wc * (BN / 2) + i * 16 + (l & 15);
      bfr[i] = *(const sv8*)(lB[cur] + rb * 32 + (((l >> 4) ^ ((rb >> 1) & 3)) * 8));
    }
    __builtin_amdgcn_s_setprio(1);
#pragma unroll
    for (int mi = 0; mi < 4; ++mi)
#pragma unroll
      for (int ni = 0; ni < NI; ++ni)
        acc[mi][ni] = __builtin_amdgcn_mfma_f32_16x16x32_bf16(af[mi], bfr[ni], acc[mi][ni], 0, 0, 0);
    __builtin_amdgcn_s_setprio(0);
    if (t + 2 < nk) {
      if constexpr (BN == 128) WAIT_VM(4); else WAIT_VM(3);
      __builtin_amdgcn_s_barrier();
    } else if (t + 1 < nk) {
      WAIT_VM(0);
      __builtin_amdgcn_s_barrier();
    }
    cur = (cur + 1 >= 3) ? 0 : cur + 1;
  }

  const int r0 = rowbase + wr * 64 + ((l >> 4) * 4);
  const int ccol = colbase + wc * (BN / 2) + (l & 15);
#pragma unroll
  for (int mi = 0; mi < 4; ++mi) {
#pragma unroll
    for (int j = 0; j < 4; ++j) {
      const size_t r = (size_t)(r0 + mi * 16 + j);
      if (GEGLU) {
#pragma unroll
        for (int p = 0; p < NI / 2; ++p) {
          const int ca = ccol + p * 32;
          const int ocol = ((ca >> 5) << 4) | (ca & 15);
          const float av = acc[mi][2 * p][j] + bias[ocol];
          const float gv = acc[mi][2 * p + 1][j] + bias[ocol + (M >> 1)];
          const float y = 0.7978845608028654f * (gv + 0.044715f * gv * gv * gv);
          const float e = exp2f(2.8853900817779268f * y);
          const float gel = gv * (1.f - 1.f / (e + 1.f));
          ((unsigned short*)Cout)[r * (size_t)(M >> 1) + ocol] = f2b(av * gel);
        }
      } else {
#pragma unroll
        for (int ni = 0; ni < NI; ++ni) {
          const int c = ccol + ni * 16;
          float vv = acc[mi][ni][j];
          if (HASBIAS) vv += bias[c];
          if (OUTF32) {
            ((float*)Cout)[r * M + c] = res[r * M + c] + vv;
          } else {
            ((unsigned short*)Cout)[r * M + c] = f2b(vv);
          }
        }
      }
    }
  }
}

// ------- 256x128 8-wave GEMM, 2-buffer depth-1 prefetch, 3 blocks/CU — W1 -------
template <int GEGLU>
__global__ __launch_bounds__(512, 4) void gemm256(const unsigned short* __restrict__ A,
                                                  const unsigned short* __restrict__ Bw,
                                                  void* __restrict__ Cout,
                                                  const float* __restrict__ bias,
                                                  int M, int K) {
  __shared__ unsigned short Ah[2][256 * 32];
  __shared__ unsigned short Bh[2][128 * 32];
  const int tid = threadIdx.x;
  const int l = tid & 63, w = tid >> 6;
  const int wrow = w >> 2, wcol = w & 3;   // 2 x 4 wave grid
  const int nbase = blockIdx.y * 256, mbase = blockIdx.x * 128;

  const fv4 zero4 = {0.f, 0.f, 0.f, 0.f};
  fv4 acc[8][2];
#pragma unroll
  for (int i = 0; i < 8; ++i) { acc[i][0] = zero4; acc[i][1] = zero4; }

  const int sA0 = tid, sA1 = tid + 512;
  const int rA0 = sA0 >> 2, xA0 = ((sA0 & 3) ^ ((rA0 >> 1) & 3)) * 8;
  const int rA1 = sA1 >> 2, xA1 = ((sA1 & 3) ^ ((rA1 >> 1) & 3)) * 8;
  const int rB = tid >> 2, xB = ((tid & 3) ^ ((rB >> 1) & 3)) * 8;
  const unsigned short* As0 = A + (size_t)(nbase + rA0) * K + xA0;
  const unsigned short* As1 = A + (size_t)(nbase + rA1) * K + xA1;
  const unsigned short* Bs = Bw + (size_t)(mbase + rB) * K + xB;

  const int nk = K >> 5;

  auto stage = [&](int buf, int kof) {
    load_lds16(As0 + kof, &Ah[buf][sA0 * 8]);
    load_lds16(As1 + kof, &Ah[buf][sA1 * 8]);
    load_lds16(Bs + kof, &Bh[buf][tid * 8]);
  };

  const int cl = (((l >> 4) ^ ((l >> 1) & 3))) * 8;
  const int arl = (wrow * 128 + (l & 15)) * 32 + cl;
  const int brl = (wcol * 32 + (l & 15)) * 32 + cl;

  stage(0, 0);
  __syncthreads();

  int cur = 0;
  for (int t = 0; t < nk; ++t) {
    const int nx = cur ^ 1;
    if (t + 1 < nk) stage(nx, (t + 1) * 32);
    sv8 af[8], b0, b1;
#pragma unroll
    for (int mi = 0; mi < 8; ++mi) af[mi] = *(const sv8*)(&Ah[cur][arl + mi * 512]);
    b0 = *(const sv8*)(&Bh[cur][brl]);
    b1 = *(const sv8*)(&Bh[cur][brl + 512]);
    __builtin_amdgcn_s_setprio(1);
#pragma unroll
    for (int mi = 0; mi < 8; ++mi) {
      acc[mi][0] = __builtin_amdgcn_mfma_f32_16x16x32_bf16(af[mi], b0, acc[mi][0], 0, 0, 0);
      acc[mi][1] = __builtin_amdgcn_mfma_f32_16x16x32_bf16(af[mi], b1, acc[mi][1], 0, 0, 0);
    }
    __builtin_amdgcn_s_setprio(0);
    __syncthreads();  // drains prefetch; all waves done reading buf[cur]
    cur = nx;
  }

  const int rbase = nbase + wrow * 128 + ((l >> 4) * 4);
  const int cbase = mbase + wcol * 32 + (l & 15);
#pragma unroll
  for (int mi = 0; mi < 8; ++mi) {
#pragma unroll
    for (int j = 0; j < 4; ++j) {
      const size_t r = (size_t)(rbase + mi * 16 + j);
      if (GEGLU) {
        const int ca = cbase;                            // even fragment (a); bit4 == 0
        const int ocol = ((ca >> 5) << 4) | (ca & 15);   // original column
        const float av = acc[mi][0][j] + bias[ocol];
        const float gv = acc[mi][1][j] + bias[ocol + (M >> 1)];
        const float y = 0.7978845608028654f * (gv + 0.044715f * gv * gv * gv);
        const float e = exp2f(2.8853900817779268f * y);  // exp(2y)
        const float gel = gv * (1.f - 1.f / (e + 1.f));  // == 0.5*g*(1+tanh(y))
        ((unsigned short*)Cout)[r * (size_t)(M >> 1) + ocol] = f2b(av * gel);
      } else {
#pragma unroll
        for (int ni = 0; ni < 2; ++ni) {
          const int c = cbase + ni * 16;
          ((unsigned short*)Cout)[r * (size_t)M + c] = f2b(acc[mi][ni][j]);
        }
      }
    }
  }
}

// ------ flash attention, swapped QK^T, in-register P, KVBLK=64 (best measured) ------
__global__ __launch_bounds__(256) void attn_kernel(const unsigned short* __restrict__ Q,
                                                   const unsigned short* __restrict__ Kb,
                                                   const unsigned short* __restrict__ vT,
                                                   unsigned short* __restrict__ O,
                                                   int ld) {
  const int bidl = ((blockIdx.x & 7) << 7) + (blockIdx.x >> 3);  // 1024 = 8 XCD x 128
  const int bh = bidl >> 5;
  const int b = bh / Hh, h = bh % Hh;
  const int q0 = (bidl & 31) * 64;
  const int tid = threadIdx.x, l = tid & 63, w = tid >> 6;
  const size_t base = (size_t)b * Tt * ld + (size_t)h * Dd;
  const size_t baseO = (size_t)b * Tt * Ee + (size_t)h * Dd;
  const unsigned short* vTb = vT + (size_t)bh * 64 * Tt;  // [64 d][2048 k']

  __shared__ unsigned short Kt[2][64 * 64];
  __shared__ unsigned short Vt[2][64 * 64];

  sv8 qf0, qf1;
  {
    const unsigned short* qp = Q + base + (size_t)(q0 + w * 16 + (l & 15)) * ld + (l >> 4) * 8;
    qf0 = *(const sv8*)qp;
    qf1 = *(const sv8*)(qp + 32);
  }

  const fv4 zero4 = {0.f, 0.f, 0.f, 0.f};
  fv4 acc_o[4];
#pragma unroll
  for (int i = 0; i < 4; ++i) acc_o[i] = zero4;
  float Mx = -INFINITY, Lp = 0.f;

  const int c0 = tid, c1 = tid + 256;
  const int r0c = c0 >> 3, xc0 = c0 & 7;
  const int r1c = c1 >> 3, xc1 = c1 & 7;

  load_lds16(Kb + base + (size_t)(r0c)*ld + (xc0 ^ (r0c & 7)) * 8, Kt[0] + c0 * 8);
  load_lds16(Kb + base + (size_t)(r1c)*ld + (xc1 ^ (r1c & 7)) * 8, Kt[0] + c1 * 8);
  load_lds16(vTb + (size_t)(r0c)*Tt + (xc0 ^ (r0c & 7)) * 8, Vt[0] + c0 * 8);
  load_lds16(vTb + (size_t)(r1c)*Tt + (xc1 ^ (r1c & 7)) * 8, Vt[0] + c1 * 8);
  __syncthreads();

  int cur = 0;
  for (int kt = 0; kt < Tt / 64; ++kt) {
    const int nx = cur ^ 1;
    if (kt + 1 < Tt / 64) {
      load_lds16(Kb + base + (size_t)((kt + 1) * 64 + r0c) * ld + (xc0 ^ (r0c & 7)) * 8, Kt[nx] + c0 * 8);
      load_lds16(Kb + base + (size_t)((kt + 1) * 64 + r1c) * ld + (xc1 ^ (r1c & 7)) * 8, Kt[nx] + c1 * 8);
      load_lds16(vTb + (size_t)(r0c)*Tt + (kt + 1) * 64 + (xc0 ^ (r0c & 7)) * 8, Vt[nx] + c0 * 8);
      load_lds16(vTb + (size_t)(r1c)*Tt + (kt + 1) * 64 + (xc1 ^ (r1c & 7)) * 8, Vt[nx] + c1 * 8);
    }

    // --- S^T = K Q^T : st[ks][j] = S[k = ks*16 + (l>>4)*4 + j][q = l&15] ---
    fv4 st[4];
    __builtin_amdgcn_s_setprio(1);
#pragma unroll
    for (int ks = 0; ks < 4; ++ks) {
      const int row = ks * 16 + (l & 15);
      const sv8 kf0 = *(const sv8*)(Kt[cur] + row * 64 + (((l >> 4) ^ (row & 7)) * 8));
      const sv8 kf1 = *(const sv8*)(Kt[cur] + row * 64 + (((4 + (l >> 4)) ^ (row & 7)) * 8));
      fv4 t = zero4;
      t = __builtin_amdgcn_mfma_f32_16x16x32_bf16(kf0, qf0, t, 0, 0, 0);
      t = __builtin_amdgcn_mfma_f32_16x16x32_bf16(kf1, qf1, t, 0, 0, 0);
      st[ks] = t;
    }
    __builtin_amdgcn_s_setprio(0);

    // --- per-q max: max3-friendly tree (v_max3_f32 fusion) + 2 cross-quarter shfl ---
    const float t0 = fmaxf(fmaxf(st[0][0], st[0][1]), st[0][2]);
    const float t1 = fmaxf(fmaxf(st[0][3], st[1][0]), st[1][1]);
    const float t2 = fmaxf(fmaxf(st[1][2], st[1][3]), st[2][0]);
    const float t3 = fmaxf(fmaxf(st[2][1], st[2][2]), st[2][3]);
    const float t4 = fmaxf(fmaxf(st[3][0], st[3][1]), st[3][2]);
    float tm = fmaxf(fmaxf(fmaxf(fmaxf(t0, t1), t2), fmaxf(t3, t4)), st[3][3]);
    tm = fmaxf(tm, __shfl_xor(tm, 16));
    tm = fmaxf(tm, __shfl_xor(tm, 32));
    if (__any(tm > Mx + 11.5f)) {
      const float mnew = fmaxf(Mx, tm);
      const float alpha = exp2f(Mx - mnew);  // tile 0: exp2(-inf) = 0
      Mx = mnew;
      Lp *= alpha;
#pragma unroll
      for (int j = 0; j < 4; ++j) {
        const float aj = __shfl(alpha, (l & 48) | ((l >> 4) * 4 + j));
#pragma unroll
        for (int dsb = 0; dsb < 4; ++dsb) acc_o[dsb][j] *= aj;
      }
    }
    // --- p = exp2(s - Mx); lane-local denominator; in-register bf16 pack ---
    float ps[4][4];
#pragma unroll
    for (int ks = 0; ks < 4; ++ks)
#pragma unroll
      for (int j = 0; j < 4; ++j) {
        const float p = exp2f(st[ks][j] - Mx);
        ps[ks][j] = p;
        Lp += p;
      }
    union PA { sv8 v8; unsigned u[4]; } pa0, pa1;
    pa0.u[0] = pkbf(ps[0][0], ps[0][1]); pa0.u[1] = pkbf(ps[0][2], ps[0][3]);
    pa0.u[2] = pkbf(ps[1][0], ps[1][1]); pa0.u[3] = pkbf(ps[1][2], ps[1][3]);
    pa1.u[0] = pkbf(ps[2][0], ps[2][1]); pa1.u[1] = pkbf(ps[2][2], ps[2][3]);
    pa1.u[2] = pkbf(ps[3][0], ps[3][1]); pa1.u[3] = pkbf(ps[3][2], ps[3][3]);

    // --- O += P V over k' (V rows pre-permuted to k' order) ---
    __builtin_amdgcn_s_setprio(1);
#pragma unroll
    for (int kcn = 0; kcn < 2; ++kcn) {
      const sv8 pf = (kcn == 0) ? pa0.v8 : pa1.v8;
#pragma unroll
      for (int dsb = 0; dsb < 4; ++dsb) {
        const int row = dsb * 16 + (l & 15);
        const int chunk = kcn * 4 + (l >> 4);
        const sv8 vf = *(const sv8*)(Vt[cur] + row * 64 + ((chunk ^ (row & 7)) * 8));
        acc_o[dsb] = __builtin_amdgcn_mfma_f32_16x16x32_bf16(pf, vf, acc_o[dsb], 0, 0, 0);
      }
    }
    __builtin_amdgcn_s_setprio(0);

    __syncthreads();
    cur = nx;
  }

  // ---- denominator: cross-quarter reduce, broadcast to output lanes ----
  float Lt = Lp;
  Lt += __shfl_xor(Lt, 16);
  Lt += __shfl_xor(Lt, 32);
#pragma unroll
  for (int j = 0; j < 4; ++j) {
    const float Lj = __shfl(Lt, (l & 48) | ((l >> 4) * 4 + j));
    const float inv = 1.f / Lj;
    unsigned short* op = O + baseO + (size_t)(q0 + w * 16 + (l >> 4) * 4 + j) * Ee;
#pragma unroll
    for (int dsb = 0; dsb < 4; ++dsb)
      op[dsb * 16 + (l & 15)] = f2b(acc_o[dsb][j] * inv);
  }
}

extern "C" void kernel_launch(void* const* d_in, const int* in_sizes, int n_in,
                              void* d_out, int out_size, void* d_ws, size_t ws_size,
                              hipStream_t stream) {
  (void)in_sizes; (void)n_in; (void)out_size; (void)ws_size;
  const float* src  = (const float*)d_in[0];
  const float* Wq   = (const float*)d_in[1];
  const float* Wk   = (const float*)d_in[2];
  const float* Wv   = (const float*)d_in[3];
  const float* Wo   = (const float*)d_in[4];
  const float* W1   = (const float*)d_in[5];
  const float* b1   = (const float*)d_in[6];
  const float* W2   = (const float*)d_in[7];
  const float* b2   = (const float*)d_in[8];
  const float* ln1w = (const float*)d_in[9];
  const float* ln1b = (const float*)d_in[10];
  const float* ln2w = (const float*)d_in[11];
  const float* ln2b = (const float*)d_in[12];
  float* out = (float*)d_out;

  char* ws = (char*)d_ws;
  size_t off = 0;
  auto alloc = [&](size_t bytes) { char* p = ws + off; off += bytes; return p; };
  unsigned short* wqkv = (unsigned short*)alloc((size_t)3 * Ee * Ee * 2);  // Wq|Wk|Wv rows
  unsigned short* wo16 = (unsigned short*)alloc((size_t)Ee * Ee * 2);
  unsigned short* w116 = (unsigned short*)alloc((size_t)2 * FFd * Ee * 2); // interleaved
  unsigned short* w216 = (unsigned short*)alloc((size_t)Ee * FFd * 2);
  unsigned short* h16  = (unsigned short*)alloc((size_t)NN * Ee * 2);
  unsigned short* qkv  = (unsigned short*)alloc((size_t)NN * 3 * Ee * 2);  // [row][3E]
  unsigned short* a16  = (unsigned short*)alloc((size_t)NN * Ee * 2);
  float* xbuf          = (float*)alloc((size_t)NN * Ee * 4);
  unsigned short* vT   = (unsigned short*)alloc((size_t)NN * Ee * 2);      // [b][h][64][T]
  unsigned short* f16  = qkv;  // reuse qkv+a16 region (32 MB) after attention done

  const float s2 = 0.125f * 1.4426950408889634f;  // 1/sqrt(D) * log2(e), folded into Wq

  dim3 blk(256);
  // all 6 weight converts in one launch
  cvt_all_kernel<<<dim3(16384), blk, 0, stream>>>(Wq, Wk, Wv, Wo, W1, W2,
                                                  wqkv, wo16, w116, w216, s2);

  ln_kernel<<<dim3(NN), blk, 0, stream>>>(src, ln1w, ln1b, h16);

  // fused QKV projection: [4096,1024] x [3072,1024]^T -> [4096,3072]
  gemm_bt<0, 0, 128, 0><<<dim3(3 * Ee / 128, NN / 128), blk, 0, stream>>>(h16, wqkv, qkv, nullptr, nullptr, 3 * Ee, Ee);

  // V transpose + k' permutation: [t][h*64+d] -> vT[b][h][d][k']
  vt_kernel<<<dim3(Tt / 64, Bb * Hh), blk, 0, stream>>>(qkv, vT);

  attn_kernel<<<dim3(1024), blk, 0, stream>>>(qkv, qkv + Ee, vT, a16, 3 * Ee);

  // Wo projection + residual (BN=64: 512 blocks, 2/CU)
  gemm_bt<1, 0, 64, 0><<<dim3(Ee / 64, NN / 128), blk, 0, stream>>>(a16, wo16, xbuf, nullptr, src, Ee, Ee);

  ln_kernel<<<dim3(NN), blk, 0, stream>>>(xbuf, ln2w, ln2b, h16);

  // W1 (block-16 interleaved) + lane-local GEGLU, 256x128 2-buffer kernel, 3 blocks/CU
  gemm256<1><<<dim3(2 * FFd / 128, NN / 256), dim3(512), 0, stream>>>(h16, w116, f16, b1, 2 * FFd, Ee);

  // W2 projection + bias + residual (BN=64: 512 blocks, 2/CU)
  gemm_bt<1, 1, 64, 0><<<dim3(Ee / 64, NN / 128), blk, 0, stream>>>(f16, w216, out, b2, xbuf, Ee, FFd);
}